// Round 2
// baseline (1448.041 us; speedup 1.0000x reference)
//
#include <hip/hip_runtime.h>

// Problem dims (fixed by the reference)
#define S_DIM 4096
#define E_DIM 1024
#define H_DIM 8

typedef __bf16 bf16x8 __attribute__((ext_vector_type(8)));
typedef float  f32x4  __attribute__((ext_vector_type(4)));

// ---------------------------------------------------------------------------
// Generic 128x128-tile bf16 MFMA GEMM, 256 threads (4 waves, 2x2 wave grid,
// 64x64 per wave as 4x4 of 16x16x32 MFMAs), BK=64.
//   C[m,n] = scale * sum_k A[m,k]*B[n,k]  (+ bias[n])
// AF32/BF32: operand source dtype is fp32 (converted to bf16 on LDS store);
//            else source is bf16.
// TA/TB: operand source is stored [K, M]/[K, N] (k-major) -> transpose-on-
//        store staging. Otherwise [M,K]/[N,K] with k contiguous.
// LDS tiles [128][72] (pad 8 bf16: 16B-aligned rows, breaks pow2 stride).
// ---------------------------------------------------------------------------
template <bool AF32, bool BF32, bool TA, bool TB, bool OUTF32>
__global__ __launch_bounds__(256) void gemm128(
    const void* __restrict__ Ag_, const void* __restrict__ Bg_,
    void* __restrict__ Cg, const float* __restrict__ biasg,
    int K, int lda, int ldb, int ldc,
    long long sA, long long sB, long long sC, long long sBias,
    float scale)
{
    __shared__ __bf16 As[128 * 72];
    __shared__ __bf16 Bs[128 * 72];

    const int tid  = threadIdx.x;
    const int lane = tid & 63;
    const int wave = tid >> 6;
    const int t    = lane & 15;
    const int quad = lane >> 4;
    const int wm   = wave >> 1;
    const int wn   = wave & 1;
    const int m0   = blockIdx.y * 128;
    const int n0   = blockIdx.x * 128;

    f32x4 acc[4][4];
#pragma unroll
    for (int i = 0; i < 4; i++)
#pragma unroll
        for (int j = 0; j < 4; j++) {
            f32x4 z = {0.f, 0.f, 0.f, 0.f};
            acc[i][j] = z;
        }

    for (int k0 = 0; k0 < K; k0 += 64) {
        // ---- stage A ----
        if (!TA) {
            const int r = tid >> 3, c = (tid & 7) << 3;
#pragma unroll
            for (int p = 0; p < 4; p++) {
                const int row = p * 32 + r;
                if constexpr (AF32) {
                    const float* src = (const float*)Ag_ + (size_t)blockIdx.z * (size_t)sA
                                       + (size_t)(m0 + row) * lda + k0 + c;
                    float4 v0 = *(const float4*)(src);
                    float4 v1 = *(const float4*)(src + 4);
                    union { __bf16 h[8]; int4 v; } u;
                    u.h[0] = (__bf16)v0.x; u.h[1] = (__bf16)v0.y;
                    u.h[2] = (__bf16)v0.z; u.h[3] = (__bf16)v0.w;
                    u.h[4] = (__bf16)v1.x; u.h[5] = (__bf16)v1.y;
                    u.h[6] = (__bf16)v1.z; u.h[7] = (__bf16)v1.w;
                    *(int4*)(&As[row * 72 + c]) = u.v;
                } else {
                    const __bf16* src = (const __bf16*)Ag_ + (size_t)blockIdx.z * (size_t)sA
                                        + (size_t)(m0 + row) * lda + k0 + c;
                    *(int4*)(&As[row * 72 + c]) = *(const int4*)src;
                }
            }
        } else {
            const int kr = tid >> 4, c = (tid & 15) << 3;
            const int rot = lane & 7;
#pragma unroll
            for (int p = 0; p < 4; p++) {
                const int krow = p * 16 + kr;
                if constexpr (AF32) {
                    const float* src = (const float*)Ag_ + (size_t)blockIdx.z * (size_t)sA
                                       + (size_t)(k0 + krow) * lda + m0 + c;
                    float4 v0 = *(const float4*)(src);
                    float4 v1 = *(const float4*)(src + 4);
                    float f[8] = {v0.x, v0.y, v0.z, v0.w, v1.x, v1.y, v1.z, v1.w};
#pragma unroll
                    for (int ii = 0; ii < 8; ii++) {
                        const int i = (ii + rot) & 7;   // rotate to spread LDS banks
                        As[(c + i) * 72 + krow] = (__bf16)f[i];
                    }
                } else {
                    const __bf16* src = (const __bf16*)Ag_ + (size_t)blockIdx.z * (size_t)sA
                                        + (size_t)(k0 + krow) * lda + m0 + c;
                    int4 v = *(const int4*)src;
                    const __bf16* pv = (const __bf16*)&v;
#pragma unroll
                    for (int ii = 0; ii < 8; ii++) {
                        const int i = (ii + rot) & 7;
                        As[(c + i) * 72 + krow] = pv[i];
                    }
                }
            }
        }
        // ---- stage B ----
        if (!TB) {
            const int r = tid >> 3, c = (tid & 7) << 3;
#pragma unroll
            for (int p = 0; p < 4; p++) {
                const int row = p * 32 + r;
                if constexpr (BF32) {
                    const float* src = (const float*)Bg_ + (size_t)blockIdx.z * (size_t)sB
                                       + (size_t)(n0 + row) * ldb + k0 + c;
                    float4 v0 = *(const float4*)(src);
                    float4 v1 = *(const float4*)(src + 4);
                    union { __bf16 h[8]; int4 v; } u;
                    u.h[0] = (__bf16)v0.x; u.h[1] = (__bf16)v0.y;
                    u.h[2] = (__bf16)v0.z; u.h[3] = (__bf16)v0.w;
                    u.h[4] = (__bf16)v1.x; u.h[5] = (__bf16)v1.y;
                    u.h[6] = (__bf16)v1.z; u.h[7] = (__bf16)v1.w;
                    *(int4*)(&Bs[row * 72 + c]) = u.v;
                } else {
                    const __bf16* src = (const __bf16*)Bg_ + (size_t)blockIdx.z * (size_t)sB
                                        + (size_t)(n0 + row) * ldb + k0 + c;
                    *(int4*)(&Bs[row * 72 + c]) = *(const int4*)src;
                }
            }
        } else {
            const int kr = tid >> 4, c = (tid & 15) << 3;
            const int rot = lane & 7;
#pragma unroll
            for (int p = 0; p < 4; p++) {
                const int krow = p * 16 + kr;
                if constexpr (BF32) {
                    const float* src = (const float*)Bg_ + (size_t)blockIdx.z * (size_t)sB
                                       + (size_t)(k0 + krow) * ldb + n0 + c;
                    float4 v0 = *(const float4*)(src);
                    float4 v1 = *(const float4*)(src + 4);
                    float f[8] = {v0.x, v0.y, v0.z, v0.w, v1.x, v1.y, v1.z, v1.w};
#pragma unroll
                    for (int ii = 0; ii < 8; ii++) {
                        const int i = (ii + rot) & 7;
                        Bs[(c + i) * 72 + krow] = (__bf16)f[i];
                    }
                } else {
                    const __bf16* src = (const __bf16*)Bg_ + (size_t)blockIdx.z * (size_t)sB
                                        + (size_t)(k0 + krow) * ldb + n0 + c;
                    int4 v = *(const int4*)src;
                    const __bf16* pv = (const __bf16*)&v;
#pragma unroll
                    for (int ii = 0; ii < 8; ii++) {
                        const int i = (ii + rot) & 7;
                        Bs[(c + i) * 72 + krow] = pv[i];
                    }
                }
            }
        }
        __syncthreads();

#pragma unroll
        for (int kk = 0; kk < 2; kk++) {
            bf16x8 af[4], bfv[4];
#pragma unroll
            for (int i = 0; i < 4; i++)
                af[i] = *(const bf16x8*)(&As[(wm * 64 + i * 16 + t) * 72 + kk * 32 + quad * 8]);
#pragma unroll
            for (int j = 0; j < 4; j++)
                bfv[j] = *(const bf16x8*)(&Bs[(wn * 64 + j * 16 + t) * 72 + kk * 32 + quad * 8]);
#pragma unroll
            for (int i = 0; i < 4; i++)
#pragma unroll
                for (int j = 0; j < 4; j++)
                    acc[i][j] = __builtin_amdgcn_mfma_f32_16x16x32_bf16(af[i], bfv[j], acc[i][j], 0, 0, 0);
        }
        __syncthreads();
    }

    // ---- epilogue: C row = m0+wm*64+i*16+quad*4+reg, col = n0+wn*64+j*16+t ----
    const float* bias = biasg ? biasg + (size_t)blockIdx.z * (size_t)sBias : nullptr;
#pragma unroll
    for (int i = 0; i < 4; i++) {
        const int rowb = m0 + wm * 64 + i * 16 + quad * 4;
#pragma unroll
        for (int j = 0; j < 4; j++) {
            const int col = n0 + wn * 64 + j * 16 + t;
            const float bv = bias ? bias[col] : 0.f;
#pragma unroll
            for (int r = 0; r < 4; r++) {
                const float v = acc[i][j][r] * scale + bv;
                if constexpr (OUTF32) {
                    float* C = (float*)Cg + (size_t)blockIdx.z * (size_t)sC;
                    C[(size_t)(rowb + r) * ldc + col] = v;
                } else {
                    __bf16* C = (__bf16*)Cg + (size_t)blockIdx.z * (size_t)sC;
                    C[(size_t)(rowb + r) * ldc + col] = (__bf16)v;
                }
            }
        }
    }
}

// ---------------------------------------------------------------------------
// Row softmax over 1024 cols; fp32 in, bf16 out. One block (256 thr) per row.
// ---------------------------------------------------------------------------
__global__ __launch_bounds__(256) void softmax_rows(
    const float* __restrict__ Sc, __bf16* __restrict__ Aout)
{
    __shared__ float red[4];
    const int row = blockIdx.x;
    const int tid = threadIdx.x, lane = tid & 63, wave = tid >> 6;

    float4 v = ((const float4*)(Sc + (size_t)row * E_DIM))[tid];
    float m = fmaxf(fmaxf(v.x, v.y), fmaxf(v.z, v.w));
#pragma unroll
    for (int o = 32; o > 0; o >>= 1) m = fmaxf(m, __shfl_down(m, o));
    if (lane == 0) red[wave] = m;
    __syncthreads();
    m = fmaxf(fmaxf(red[0], red[1]), fmaxf(red[2], red[3]));
    __syncthreads();

    const float e0 = __expf(v.x - m), e1 = __expf(v.y - m);
    const float e2 = __expf(v.z - m), e3 = __expf(v.w - m);
    float s = e0 + e1 + e2 + e3;
#pragma unroll
    for (int o = 32; o > 0; o >>= 1) s += __shfl_down(s, o);
    if (lane == 0) red[wave] = s;
    __syncthreads();
    s = red[0] + red[1] + red[2] + red[3];
    const float inv = 1.f / s;

    __bf16* out = Aout + (size_t)row * E_DIM + tid * 4;
    out[0] = (__bf16)(e0 * inv);
    out[1] = (__bf16)(e1 * inv);
    out[2] = (__bf16)(e2 * inv);
    out[3] = (__bf16)(e3 * inv);
}

// ---------------------------------------------------------------------------
// Fused LayerNorm + residual: outF = LN(X)*g + b + resid (all fp32).
// WRITE_BF16: also write a bf16 copy (feeds the next GEMM). 1 block/row.
// ---------------------------------------------------------------------------
template <bool WRITE_BF16>
__global__ __launch_bounds__(256) void ln_residual(
    const float* __restrict__ X, const float* __restrict__ resid,
    const float* __restrict__ g, const float* __restrict__ b,
    __bf16* __restrict__ outB, float* __restrict__ outF)
{
    __shared__ float redS[4], redQ[4];
    const int row = blockIdx.x;
    const int tid = threadIdx.x, lane = tid & 63, wave = tid >> 6;

    float4 v = ((const float4*)(X + (size_t)row * E_DIM))[tid];
    float s = v.x + v.y + v.z + v.w;
    float q = v.x * v.x + v.y * v.y + v.z * v.z + v.w * v.w;
#pragma unroll
    for (int o = 32; o > 0; o >>= 1) {
        s += __shfl_down(s, o);
        q += __shfl_down(q, o);
    }
    if (lane == 0) { redS[wave] = s; redQ[wave] = q; }
    __syncthreads();
    s = redS[0] + redS[1] + redS[2] + redS[3];
    q = redQ[0] + redQ[1] + redQ[2] + redQ[3];

    const float mean = s * (1.f / E_DIM);
    const float var  = q * (1.f / E_DIM) - mean * mean;
    const float rstd = rsqrtf(var + 1e-5f);

    const int c0 = tid * 4;
    float4 rv = ((const float4*)(resid + (size_t)row * E_DIM))[tid];
    const float res[4] = {rv.x, rv.y, rv.z, rv.w};
    const float* vp = &v.x;
#pragma unroll
    for (int i = 0; i < 4; i++) {
        const float o = (vp[i] - mean) * rstd * g[c0 + i] + b[c0 + i] + res[i];
        outF[(size_t)row * E_DIM + c0 + i] = o;
        if constexpr (WRITE_BF16) outB[(size_t)row * E_DIM + c0 + i] = (__bf16)o;
    }
}

// ---------------------------------------------------------------------------
extern "C" void kernel_launch(void* const* d_in, const int* in_sizes, int n_in,
                              void* d_out, int out_size, void* d_ws, size_t ws_size,
                              hipStream_t stream)
{
    // All inputs/outputs are fp32 (reference dtype). bf16 only internally.
    const float* x   = (const float*)d_in[0];
    const float* Wq  = (const float*)d_in[1];
    const float* bq  = (const float*)d_in[2];
    const float* Wk  = (const float*)d_in[3];
    const float* bk  = (const float*)d_in[4];
    const float* Wv  = (const float*)d_in[5];
    const float* bv  = (const float*)d_in[6];
    const float* Wz  = (const float*)d_in[7];
    const float* bz  = (const float*)d_in[8];
    const float* g1  = (const float*)d_in[9];
    const float* b1  = (const float*)d_in[10];
    const float* Wf  = (const float*)d_in[11];
    const float* bfp = (const float*)d_in[12];
    const float* g2  = (const float*)d_in[13];
    const float* b2  = (const float*)d_in[14];

    char* ws = (char*)d_ws;
    const size_t SE  = (size_t)S_DIM * E_DIM;          // 4,194,304
    const long long EE = (long long)E_DIM * E_DIM;     // 1,048,576

    // Workspace (peak exactly 200 MiB), liveness-based aliasing:
    __bf16* Qb   = (__bf16*)(ws);                      // [H,S,E] bf16, 64 MiB
    __bf16* Kb   = (__bf16*)(ws +  67108864ull);       // [H,S,E] bf16, 64 MiB
    float*  Sc   = (float*) (ws + 134217728ull);       // [H,E,E] fp32, 32 MiB
    __bf16* Ab   = (__bf16*)(ws + 167772160ull);       // [H,E,E] bf16, 16 MiB
    __bf16* Vb   = Qb;                                 // aliases Q (dead after scores)
    __bf16* Zb   = Kb;                                 // aliases K (dead after scores)
    float*  Ob   = Sc;                                 // aliases Sc (dead after softmax)
    float*  FNb  = (float*) (ws + 150994944ull);       // Sc 2nd half
    __bf16* LN1b = (__bf16*)(ws + 184549376ull);       // 8 MiB
    float*  LN1f = (float*) (ws + 192937984ull);       // 16 MiB -> total 200 MiB

    dim3 blk(256);
    dim3 gQKV(E_DIM / 128, S_DIM / 128, H_DIM);
    dim3 gS(E_DIM / 128, E_DIM / 128, H_DIM);
    dim3 gO(E_DIM / 128, S_DIM / 128, 1);

    // 1) Q = x@Wq^T + bq ; K = x@Wk^T + bk   (fp32 src -> bf16 out)
    gemm128<true, true, false, false, false><<<gQKV, blk, 0, stream>>>(
        x, Wq, (void*)Qb, bq, E_DIM, E_DIM, E_DIM, E_DIM,
        0LL, EE, (long long)SE, (long long)E_DIM, 1.0f);
    gemm128<true, true, false, false, false><<<gQKV, blk, 0, stream>>>(
        x, Wk, (void*)Kb, bk, E_DIM, E_DIM, E_DIM, E_DIM,
        0LL, EE, (long long)SE, (long long)E_DIM, 1.0f);

    // 2) scores[h] = K[h]^T Q[h] / 32  (TN over S; fp32 out)
    gemm128<false, false, true, true, true><<<gS, blk, 0, stream>>>(
        Kb, Qb, (void*)Sc, nullptr, S_DIM, E_DIM, E_DIM, E_DIM,
        (long long)SE, (long long)SE, EE, 0LL, 0.03125f);

    // 3) A = softmax_rows(scores)  -> bf16
    softmax_rows<<<dim3(H_DIM * E_DIM), blk, 0, stream>>>(Sc, Ab);

    // 4) V = x@Wv^T + bv   (writes over dead Q)
    gemm128<true, true, false, false, false><<<gQKV, blk, 0, stream>>>(
        x, Wv, (void*)Vb, bv, E_DIM, E_DIM, E_DIM, E_DIM,
        0LL, EE, (long long)SE, (long long)E_DIM, 1.0f);

    // 5) Z[s, h*E+f] = sum_e V[h,s,e] A[h,e,f]   (writes over dead K)
    gemm128<false, false, false, true, false><<<gQKV, blk, 0, stream>>>(
        Vb, Ab, (void*)Zb, nullptr, E_DIM, E_DIM, E_DIM, H_DIM * E_DIM,
        (long long)SE, EE, (long long)E_DIM, 0LL, 1.0f);

    // 6) O = Z @ Wz^T + bz  (K=8192; fp32 out over dead Sc)
    gemm128<false, true, false, false, true><<<gO, blk, 0, stream>>>(
        Zb, Wz, (void*)Ob, bz, H_DIM * E_DIM, H_DIM * E_DIM, H_DIM * E_DIM, E_DIM,
        0LL, 0LL, 0LL, 0LL, 1.0f);

    // 7) LN1 = LN(O)*g1+b1 + x  -> bf16 (GEMM input) + fp32 (residual)
    ln_residual<true><<<dim3(S_DIM), blk, 0, stream>>>(Ob, x, g1, b1, LN1b, LN1f);

    // 8) FN = LN1 @ Wf^T + bf -> fp32
    gemm128<false, true, false, false, true><<<gO, blk, 0, stream>>>(
        LN1b, Wf, (void*)FNb, bfp, E_DIM, E_DIM, E_DIM, E_DIM,
        0LL, 0LL, 0LL, 0LL, 1.0f);

    // 9) out = LN(FN)*g2+b2 + LN1 -> fp32 d_out
    ln_residual<false><<<dim3(S_DIM), blk, 0, stream>>>(
        FNb, LN1f, g2, b2, nullptr, (float*)d_out);
}

// Round 3
// 907.726 us; speedup vs baseline: 1.5952x; 1.5952x over previous
//
#include <hip/hip_runtime.h>

#define S_DIM 4096
#define E_DIM 1024
#define H_DIM 8

typedef __bf16 bf16x8 __attribute__((ext_vector_type(8)));
typedef float  f32x4  __attribute__((ext_vector_type(4)));

// ---------------------------------------------------------------------------
// Operand staging into LDS tile [128 mn][72 k-stride] (bf16).
// MODE 0: bf16 NT  ([mn,k] k-contig, b128 copy)
// MODE 1: fp32 NT  (convert on store)
// MODE 2: bf16 TN  ([k,mn] k-major: transpose via packed b64 writes)
// MODE 3: fp32 TN  (convert + transpose)
// ---------------------------------------------------------------------------
template <int MODE>
__device__ __forceinline__ void stage_op(const void* __restrict__ src, int ld,
                                         int mn0, int k0, __bf16* lds, int tid)
{
    if constexpr (MODE <= 1) {
        const int r = tid >> 3, c = (tid & 7) << 3;
#pragma unroll
        for (int p = 0; p < 4; p++) {
            const int row = p * 32 + r;
            if constexpr (MODE == 1) {
                const float* s = (const float*)src + (size_t)(mn0 + row) * ld + k0 + c;
                float4 v0 = *(const float4*)s, v1 = *(const float4*)(s + 4);
                union { __bf16 h[8]; int4 v; } u;
                u.h[0]=(__bf16)v0.x; u.h[1]=(__bf16)v0.y; u.h[2]=(__bf16)v0.z; u.h[3]=(__bf16)v0.w;
                u.h[4]=(__bf16)v1.x; u.h[5]=(__bf16)v1.y; u.h[6]=(__bf16)v1.z; u.h[7]=(__bf16)v1.w;
                *(int4*)&lds[row * 72 + c] = u.v;
            } else {
                const __bf16* s = (const __bf16*)src + (size_t)(mn0 + row) * ld + k0 + c;
                *(int4*)&lds[row * 72 + c] = *(const int4*)s;
            }
        }
    } else {
        // cols mn0 + (tid&15)*8 .. +8 ; krows k0 + (tid>>4)*4 .. +4
        const int cg = tid & 15, kg = tid >> 4;
        __bf16 h[4][8];
#pragma unroll
        for (int r = 0; r < 4; r++) {
            const int krow = k0 + kg * 4 + r;
            if constexpr (MODE == 3) {
                const float* s = (const float*)src + (size_t)krow * ld + mn0 + cg * 8;
                float4 v0 = *(const float4*)s, v1 = *(const float4*)(s + 4);
                h[r][0]=(__bf16)v0.x; h[r][1]=(__bf16)v0.y; h[r][2]=(__bf16)v0.z; h[r][3]=(__bf16)v0.w;
                h[r][4]=(__bf16)v1.x; h[r][5]=(__bf16)v1.y; h[r][6]=(__bf16)v1.z; h[r][7]=(__bf16)v1.w;
            } else {
                const __bf16* s = (const __bf16*)src + (size_t)krow * ld + mn0 + cg * 8;
                *(int4*)&h[r][0] = *(const int4*)s;
            }
        }
        const int rot = cg & 7;
#pragma unroll
        for (int jj = 0; jj < 8; jj++) {
            const int j = (jj + rot) & 7;   // rotate cols to spread banks (~4-way max)
            union { __bf16 q[4]; unsigned long long v; } u;
            u.q[0]=h[0][j]; u.q[1]=h[1][j]; u.q[2]=h[2][j]; u.q[3]=h[3][j];
            *(unsigned long long*)&lds[(cg * 8 + j) * 72 + kg * 4] = u.v;
        }
    }
}

// ---------------------------------------------------------------------------
// 128x128-tile bf16 MFMA GEMM: C[m,n] = scale*sum_k A[m,k]B[n,k] (+bias[n]).
// OUT: 0=bf16 store, 1=fp32 store, 2=fp32 atomicAdd (split-K; bias ignored).
// kPerZ>0: blockIdx.z selects K-chunk (split-K); else z indexes batch via
// element strides sA/sB/sC.
// ---------------------------------------------------------------------------
template <int AM, int BM, int OUT>
__global__ __launch_bounds__(256) void gemm128(
    const void* __restrict__ Ag, const void* __restrict__ Bg,
    void* __restrict__ Cg, const float* __restrict__ biasg,
    int Klen, int kPerZ, int lda, int ldb, int ldc,
    long long sA, long long sB, long long sC, float scale)
{
    __shared__ __bf16 As[128 * 72];
    __shared__ __bf16 Bs[128 * 72];

    const int tid  = threadIdx.x;
    const int lane = tid & 63;
    const int wave = tid >> 6;
    const int t    = lane & 15;
    const int quad = lane >> 4;
    const int wm   = wave >> 1;
    const int wn   = wave & 1;
    const int m0   = blockIdx.y * 128;
    const int n0   = blockIdx.x * 128;
    const size_t zi = blockIdx.z;

    const void* A = (AM == 1 || AM == 3) ? (const void*)((const float*)Ag + zi * sA)
                                         : (const void*)((const __bf16*)Ag + zi * sA);
    const void* B = (BM == 1 || BM == 3) ? (const void*)((const float*)Bg + zi * sB)
                                         : (const void*)((const __bf16*)Bg + zi * sB);
    const int kbeg = kPerZ ? (int)zi * kPerZ : 0;

    f32x4 acc[4][4];
#pragma unroll
    for (int i = 0; i < 4; i++)
#pragma unroll
        for (int j = 0; j < 4; j++) { f32x4 z = {0.f,0.f,0.f,0.f}; acc[i][j] = z; }

    for (int k0 = kbeg; k0 < kbeg + Klen; k0 += 64) {
        stage_op<AM>(A, lda, m0, k0, As, tid);
        stage_op<BM>(B, ldb, n0, k0, Bs, tid);
        __syncthreads();
#pragma unroll
        for (int kk = 0; kk < 2; kk++) {
            bf16x8 af[4], bfv[4];
#pragma unroll
            for (int i = 0; i < 4; i++)
                af[i] = *(const bf16x8*)(&As[(wm*64 + i*16 + t) * 72 + kk*32 + quad*8]);
#pragma unroll
            for (int j = 0; j < 4; j++)
                bfv[j] = *(const bf16x8*)(&Bs[(wn*64 + j*16 + t) * 72 + kk*32 + quad*8]);
#pragma unroll
            for (int i = 0; i < 4; i++)
#pragma unroll
                for (int j = 0; j < 4; j++)
                    acc[i][j] = __builtin_amdgcn_mfma_f32_16x16x32_bf16(af[i], bfv[j], acc[i][j], 0, 0, 0);
        }
        __syncthreads();
    }

#pragma unroll
    for (int i = 0; i < 4; i++) {
        const int rowb = m0 + wm*64 + i*16 + quad*4;
#pragma unroll
        for (int j = 0; j < 4; j++) {
            const int col = n0 + wn*64 + j*16 + t;
            const float bv = biasg ? biasg[col] : 0.f;
#pragma unroll
            for (int r = 0; r < 4; r++) {
                const float v = acc[i][j][r] * scale + bv;
                if constexpr (OUT == 0) {
                    __bf16* C = (__bf16*)Cg + zi * sC;
                    C[(size_t)(rowb + r) * ldc + col] = (__bf16)v;
                } else if constexpr (OUT == 1) {
                    float* C = (float*)Cg + zi * sC;
                    C[(size_t)(rowb + r) * ldc + col] = v;
                } else {
                    float* C = (float*)Cg + zi * sC;
                    atomicAdd(&C[(size_t)(rowb + r) * ldc + col], v);
                }
            }
        }
    }
}

// u[e] = sum_s x[s][e].  64 blocks x 64 rows; u pre-zeroed.
__global__ __launch_bounds__(256) void colsum_u(const float* __restrict__ x, float* __restrict__ u)
{
    const int c = threadIdx.x * 4;
    float4 a = {0.f,0.f,0.f,0.f};
    const int r0 = blockIdx.x * 64;
    for (int r = 0; r < 64; r++) {
        float4 v = *(const float4*)(x + (size_t)(r0 + r) * E_DIM + c);
        a.x += v.x; a.y += v.y; a.z += v.z; a.w += v.w;
    }
    atomicAdd(&u[c+0], a.x); atomicAdd(&u[c+1], a.y);
    atomicAdd(&u[c+2], a.z); atomicAdd(&u[c+3], a.w);
}

// kq[r] = Wk[r,:]·u ; qq[r] = Wq[r,:]·u  (r = h*E+j, 8192 rows each)
__global__ __launch_bounds__(256) void gemv_u(
    const float* __restrict__ Wk, const float* __restrict__ Wq,
    const float* __restrict__ u, float* __restrict__ kq, float* __restrict__ qq)
{
    const int gw = blockIdx.x * 4 + (threadIdx.x >> 6);
    const int lane = threadIdx.x & 63;
    const float* W = (gw < 8192) ? Wk + (size_t)gw * E_DIM
                                 : Wq + (size_t)(gw - 8192) * E_DIM;
    float s = 0.f;
#pragma unroll
    for (int i = 0; i < 4; i++) {
        float4 w = *(const float4*)(W + lane*16 + i*4);
        float4 z = *(const float4*)(u + lane*16 + i*4);
        s += w.x*z.x + w.y*z.y + w.z*z.z + w.w*z.w;
    }
#pragma unroll
    for (int o = 32; o > 0; o >>= 1) s += __shfl_down(s, o);
    if (lane == 0) { if (gw < 8192) kq[gw] = s; else qq[gw - 8192] = s; }
}

// zb[h*E+f] = sum_o bv[h][o] * A[h][o][f]; zb pre-zeroed. grid (4,8,4)
__global__ __launch_bounds__(256) void colsum_zb(
    const __bf16* __restrict__ Ab, const float* __restrict__ bv, float* __restrict__ zb)
{
    const int h = blockIdx.y;
    const int f = blockIdx.x * 256 + threadIdx.x;
    const int o0 = blockIdx.z * 256;
    const __bf16* A = Ab + (size_t)h * E_DIM * E_DIM + (size_t)o0 * E_DIM + f;
    const float* bvh = bv + h * E_DIM + o0;
    float s = 0.f;
    for (int o = 0; o < 256; o++) s += bvh[o] * (float)A[(size_t)o * E_DIM];
    atomicAdd(&zb[h * E_DIM + f], s);
}

// oc[g] = zb·Wz[g,:] + bz[g]   (K=8192, one wave per row)
__global__ __launch_bounds__(256) void gemv_oc(
    const float* __restrict__ Wz, const float* __restrict__ zb,
    const float* __restrict__ bz, float* __restrict__ oc)
{
    const int gw = blockIdx.x * 4 + (threadIdx.x >> 6);
    const int lane = threadIdx.x & 63;
    const float* W = Wz + (size_t)gw * (H_DIM * E_DIM);
    float s = 0.f;
#pragma unroll
    for (int i = 0; i < 32; i++) {
        float4 w = *(const float4*)(W + i*256 + lane*4);
        float4 z = *(const float4*)(zb + i*256 + lane*4);
        s += w.x*z.x + w.y*z.y + w.z*z.z + w.w*z.w;
    }
#pragma unroll
    for (int o = 32; o > 0; o >>= 1) s += __shfl_down(s, o);
    if (lane == 0) oc[gw] = s + bz[gw];
}

// softmax over f with fused rank-1 bias terms and 1/sqrt(E) scale.
// row = h*E + j. val = (raw + kq_j*bq_f + bk_j*qq_f + S*bk_j*bq_f)/32
__global__ __launch_bounds__(256) void softmax_fused(
    const float* __restrict__ Sc, const float* __restrict__ kq,
    const float* __restrict__ qq, const float* __restrict__ bk,
    const float* __restrict__ bq, __bf16* __restrict__ Aout)
{
    __shared__ float red[4];
    const int row = blockIdx.x;
    const int h = row >> 10;
    const int tid = threadIdx.x, lane = tid & 63, wave = tid >> 6;
    const float kqj = kq[row], bkj = bk[row];
    const float cst = (float)S_DIM * bkj;

    float4 v = ((const float4*)(Sc + (size_t)row * E_DIM))[tid];
    const int c = tid * 4;
    float4 qv = *(const float4*)(qq + (h << 10) + c);
    float4 bv = *(const float4*)(bq + (h << 10) + c);
    v.x = (v.x + kqj*bv.x + bkj*qv.x + cst*bv.x) * 0.03125f;
    v.y = (v.y + kqj*bv.y + bkj*qv.y + cst*bv.y) * 0.03125f;
    v.z = (v.z + kqj*bv.z + bkj*qv.z + cst*bv.z) * 0.03125f;
    v.w = (v.w + kqj*bv.w + bkj*qv.w + cst*bv.w) * 0.03125f;

    float m = fmaxf(fmaxf(v.x, v.y), fmaxf(v.z, v.w));
#pragma unroll
    for (int o = 32; o > 0; o >>= 1) m = fmaxf(m, __shfl_down(m, o));
    if (lane == 0) red[wave] = m;
    __syncthreads();
    m = fmaxf(fmaxf(red[0], red[1]), fmaxf(red[2], red[3]));
    __syncthreads();

    const float e0 = __expf(v.x - m), e1 = __expf(v.y - m);
    const float e2 = __expf(v.z - m), e3 = __expf(v.w - m);
    float s = e0 + e1 + e2 + e3;
#pragma unroll
    for (int o = 32; o > 0; o >>= 1) s += __shfl_down(s, o);
    if (lane == 0) red[wave] = s;
    __syncthreads();
    s = red[0] + red[1] + red[2] + red[3];
    const float inv = 1.f / s;

    __bf16* out = Aout + (size_t)row * E_DIM + c;
    out[0] = (__bf16)(e0*inv); out[1] = (__bf16)(e1*inv);
    out[2] = (__bf16)(e2*inv); out[3] = (__bf16)(e3*inv);
}

// LN + residual (fp32 in/out, optional bf16 copy)
template <bool WRITE_BF16>
__global__ __launch_bounds__(256) void ln_residual(
    const float* __restrict__ X, const float* __restrict__ resid,
    const float* __restrict__ g, const float* __restrict__ b,
    __bf16* __restrict__ outB, float* __restrict__ outF)
{
    __shared__ float redS[4], redQ[4];
    const int row = blockIdx.x;
    const int tid = threadIdx.x, lane = tid & 63, wave = tid >> 6;

    float4 v = ((const float4*)(X + (size_t)row * E_DIM))[tid];
    float s = v.x + v.y + v.z + v.w;
    float q = v.x*v.x + v.y*v.y + v.z*v.z + v.w*v.w;
#pragma unroll
    for (int o = 32; o > 0; o >>= 1) { s += __shfl_down(s, o); q += __shfl_down(q, o); }
    if (lane == 0) { redS[wave] = s; redQ[wave] = q; }
    __syncthreads();
    s = redS[0]+redS[1]+redS[2]+redS[3];
    q = redQ[0]+redQ[1]+redQ[2]+redQ[3];

    const float mean = s * (1.f / E_DIM);
    const float var  = q * (1.f / E_DIM) - mean * mean;
    const float rstd = rsqrtf(var + 1e-5f);

    const int c0 = tid * 4;
    float4 rv = ((const float4*)(resid + (size_t)row * E_DIM))[tid];
    const float res[4] = {rv.x, rv.y, rv.z, rv.w};
    const float* vp = &v.x;
#pragma unroll
    for (int i = 0; i < 4; i++) {
        const float o = (vp[i] - mean) * rstd * g[c0+i] + b[c0+i] + res[i];
        outF[(size_t)row * E_DIM + c0 + i] = o;
        if constexpr (WRITE_BF16) outB[(size_t)row * E_DIM + c0 + i] = (__bf16)o;
    }
}

// ---------------------------------------------------------------------------
extern "C" void kernel_launch(void* const* d_in, const int* in_sizes, int n_in,
                              void* d_out, int out_size, void* d_ws, size_t ws_size,
                              hipStream_t stream)
{
    const float* x   = (const float*)d_in[0];
    const float* Wq  = (const float*)d_in[1];
    const float* bq  = (const float*)d_in[2];
    const float* Wk  = (const float*)d_in[3];
    const float* bk  = (const float*)d_in[4];
    const float* Wv  = (const float*)d_in[5];
    const float* bv  = (const float*)d_in[6];
    const float* Wz  = (const float*)d_in[7];
    const float* bz  = (const float*)d_in[8];
    const float* g1  = (const float*)d_in[9];
    const float* b1  = (const float*)d_in[10];
    const float* Wf  = (const float*)d_in[11];
    const float* bfp = (const float*)d_in[12];
    const float* g2  = (const float*)d_in[13];
    const float* b2  = (const float*)d_in[14];

    char* ws = (char*)d_ws;
    const long long EE = (long long)E_DIM * E_DIM;
    const size_t MB = 1024ull * 1024ull;

    float*  Gf   = (float*) (ws);                 //  4 MiB  x^T x
    float*  PTf  = (float*) (ws + 4*MB);          //  4 MiB  P^T[g][e]
    float*  u    = (float*) (ws + 8*MB);          //  4 KiB
    float*  kq   = (float*) (ws + 8*MB + 65536);  // 32 KiB
    float*  qq   = (float*) (ws + 8*MB + 131072); // 32 KiB
    float*  zb   = (float*) (ws + 8*MB + 196608); // 32 KiB
    float*  oc   = (float*) (ws + 8*MB + 262144); //  4 KiB
    __bf16* Tb   = (__bf16*)(ws + 16*MB);         // 16 MiB  Wk_h G
    float*  Sc   = (float*) (ws + 32*MB);         // 32 MiB  raw scores
    __bf16* Ab   = (__bf16*)(ws + 64*MB);         // 16 MiB  softmax
    __bf16* Mcat = (__bf16*)(ws + 80*MB);         // 16 MiB  [e][h*E+f]
    float*  Ob   = (float*) (ws + 96*MB);         // 16 MiB
    __bf16* LN1b = (__bf16*)(ws + 112*MB);        //  8 MiB
    float*  LN1f = (float*) (ws + 120*MB);        // 16 MiB
    float*  FNb  = (float*) (ws + 136*MB);        // 16 MiB  (end 152 MiB)

    dim3 blk(256);
    dim3 gEE(8, 8, 8);          // per-head / split-K EEE GEMMs
    dim3 gSE(8, 32, 1);         // [S,E] output GEMMs

    // zero split-K accumulators + vector accumulators (ws is 0xAA-poisoned)
    hipMemsetAsync(Gf,  0, 4*MB, stream);
    hipMemsetAsync(PTf, 0, 4*MB, stream);
    hipMemsetAsync(u,   0, E_DIM*4, stream);
    hipMemsetAsync(zb,  0, H_DIM*E_DIM*4, stream);

    // u = colsum(x)
    colsum_u<<<dim3(64), blk, 0, stream>>>(x, u);
    // G = x^T x  (TN both fp32, split-K 8x512, atomic f32)
    gemm128<3, 3, 2><<<gEE, blk, 0, stream>>>(
        x, x, (void*)Gf, nullptr, 512, 512, E_DIM, E_DIM, E_DIM, 0, 0, 0, 1.f);
    // kq = Wk u ; qq = Wq u
    gemv_u<<<dim3(4096), blk, 0, stream>>>(Wk, Wq, u, kq, qq);
    // T_h = Wk_h G  (B uses G symmetry: no transpose)
    gemm128<1, 1, 0><<<gEE, blk, 0, stream>>>(
        Wk, Gf, (void*)Tb, nullptr, E_DIM, 0, E_DIM, E_DIM, E_DIM, EE, 0, EE, 1.f);
    // scores_raw_h = T_h Wq_h^T
    gemm128<0, 1, 1><<<gEE, blk, 0, stream>>>(
        Tb, Wq, (void*)Sc, nullptr, E_DIM, 0, E_DIM, E_DIM, E_DIM, EE, EE, EE, 1.f);
    // A_h = softmax((scores_raw + rank1)/32)
    softmax_fused<<<dim3(H_DIM * E_DIM), blk, 0, stream>>>(Sc, kq, qq, bk, bq, Ab);
    // Mcat[e][h*E+f] = (Wv_h^T A_h)[e][f]  (TN both)
    gemm128<3, 2, 0><<<gEE, blk, 0, stream>>>(
        Wv, Ab, (void*)Mcat, nullptr, E_DIM, 0, E_DIM, E_DIM, H_DIM * E_DIM,
        EE, EE, E_DIM, 1.f);
    // zb = bv^T A  ;  oc = Wz zb + bz
    colsum_zb<<<dim3(4, 8, 4), blk, 0, stream>>>(Ab, bv, zb);
    gemv_oc<<<dim3(256), blk, 0, stream>>>(Wz, zb, bz, oc);
    // PT[g][e] = sum_F Wz[g][F] Mcat[e][F]  (split-K 8x1024, atomic f32)
    gemm128<1, 0, 2><<<gEE, blk, 0, stream>>>(
        Wz, Mcat, (void*)PTf, nullptr, 1024, 1024, H_DIM * E_DIM, H_DIM * E_DIM,
        E_DIM, 0, 0, 0, 1.f);
    // O = x PT^T + oc
    gemm128<1, 1, 1><<<gSE, blk, 0, stream>>>(
        x, PTf, (void*)Ob, oc, E_DIM, 0, E_DIM, E_DIM, E_DIM, 0, 0, 0, 1.f);
    // LN1 = LN(O) + x
    ln_residual<true><<<dim3(S_DIM), blk, 0, stream>>>(Ob, x, g1, b1, LN1b, LN1f);
    // FN = LN1 Wf^T + bf
    gemm128<0, 1, 1><<<gSE, blk, 0, stream>>>(
        LN1b, Wf, (void*)FNb, bfp, E_DIM, 0, E_DIM, E_DIM, E_DIM, 0, 0, 0, 1.f);
    // out = LN(FN) + LN1
    ln_residual<false><<<dim3(S_DIM), blk, 0, stream>>>(
        FNb, LN1f, g2, b2, nullptr, (float*)d_out);
}

// Round 4
// 554.830 us; speedup vs baseline: 2.6099x; 1.6360x over previous
//
#include <hip/hip_runtime.h>

#define S_DIM 4096
#define E_DIM 1024
#define H_DIM 8

typedef __bf16 bf16x8 __attribute__((ext_vector_type(8)));
typedef float  f32x4  __attribute__((ext_vector_type(4)));

// ---------------------------------------------------------------------------
// Operand staging into LDS tile [128 mn][72 k-stride] (bf16).
// MODE 0: bf16 NT  ([mn,k] k-contig, b128 copy)
// MODE 1: fp32 NT  (convert on store)
// MODE 2: bf16 TN  ([k,mn] k-major: transpose, packed b64, STATIC XOR swizzle)
// MODE 3: fp32 TN  (convert + transpose, static swizzle)
// TN tiles store true column c at LDS row (c&~7)|((c&7)^((c>>3)&7)); readers
// must apply the same (involutive) swizzle. All h[][] indices compile-time.
// ---------------------------------------------------------------------------
template <int MODE>
__device__ __forceinline__ void stage_op(const void* __restrict__ src, int ld,
                                         int mn0, int k0, __bf16* lds, int tid)
{
    if constexpr (MODE <= 1) {
        const int r = tid >> 3, c = (tid & 7) << 3;
#pragma unroll
        for (int p = 0; p < 4; p++) {
            const int row = p * 32 + r;
            if constexpr (MODE == 1) {
                const float* s = (const float*)src + (size_t)(mn0 + row) * ld + k0 + c;
                float4 v0 = *(const float4*)s, v1 = *(const float4*)(s + 4);
                union { __bf16 h[8]; int4 v; } u;
                u.h[0]=(__bf16)v0.x; u.h[1]=(__bf16)v0.y; u.h[2]=(__bf16)v0.z; u.h[3]=(__bf16)v0.w;
                u.h[4]=(__bf16)v1.x; u.h[5]=(__bf16)v1.y; u.h[6]=(__bf16)v1.z; u.h[7]=(__bf16)v1.w;
                *(int4*)&lds[row * 72 + c] = u.v;
            } else {
                const __bf16* s = (const __bf16*)src + (size_t)(mn0 + row) * ld + k0 + c;
                *(int4*)&lds[row * 72 + c] = *(const int4*)s;
            }
        }
    } else {
        // cols mn0 + (tid&15)*8 .. +8 ; krows k0 + (tid>>4)*4 .. +4
        const int cg = tid & 15, kg = tid >> 4;
        __bf16 h[4][8];
#pragma unroll
        for (int r = 0; r < 4; r++) {
            const int krow = k0 + kg * 4 + r;
            if constexpr (MODE == 3) {
                const float* s = (const float*)src + (size_t)krow * ld + mn0 + cg * 8;
                float4 v0 = *(const float4*)s, v1 = *(const float4*)(s + 4);
                h[r][0]=(__bf16)v0.x; h[r][1]=(__bf16)v0.y; h[r][2]=(__bf16)v0.z; h[r][3]=(__bf16)v0.w;
                h[r][4]=(__bf16)v1.x; h[r][5]=(__bf16)v1.y; h[r][6]=(__bf16)v1.z; h[r][7]=(__bf16)v1.w;
            } else {
                const __bf16* s = (const __bf16*)src + (size_t)krow * ld + mn0 + cg * 8;
                *(int4*)&h[r][0] = *(const int4*)s;
            }
        }
        const int xr = cg & 7;
#pragma unroll
        for (int j = 0; j < 8; j++) {            // j static -> h[][] in VGPRs
            union { __bf16 q[4]; unsigned long long v; } u;
            u.q[0]=h[0][j]; u.q[1]=h[1][j]; u.q[2]=h[2][j]; u.q[3]=h[3][j];
            const int scol = cg * 8 + (j ^ xr);  // swizzle in address only
            *(unsigned long long*)&lds[scol * 72 + kg * 4] = u.v;
        }
    }
}

// ---------------------------------------------------------------------------
// 128x128-tile bf16 MFMA GEMM: C[m,n] = scale*sum_k A[m,k]B[n,k] (+bias[n]).
// OUT: 0=bf16 store, 1=fp32 store, 2=fp32 atomicAdd (split-K; bias ignored).
// kPerZ>0: blockIdx.z selects K-chunk (split-K); else z indexes batch via
// element strides sA/sB/sC.
// ---------------------------------------------------------------------------
template <int AM, int BM, int OUT>
__global__ __launch_bounds__(256) void gemm128(
    const void* __restrict__ Ag, const void* __restrict__ Bg,
    void* __restrict__ Cg, const float* __restrict__ biasg,
    int Klen, int kPerZ, int lda, int ldb, int ldc,
    long long sA, long long sB, long long sC, float scale)
{
    __shared__ __bf16 As[128 * 72];
    __shared__ __bf16 Bs[128 * 72];

    const int tid  = threadIdx.x;
    const int lane = tid & 63;
    const int wave = tid >> 6;
    const int t    = lane & 15;
    const int quad = lane >> 4;
    const int wm   = wave >> 1;
    const int wn   = wave & 1;
    const int m0   = blockIdx.y * 128;
    const int n0   = blockIdx.x * 128;
    const size_t zi = blockIdx.z;

    const void* A = (AM == 1 || AM == 3) ? (const void*)((const float*)Ag + zi * sA)
                                         : (const void*)((const __bf16*)Ag + zi * sA);
    const void* B = (BM == 1 || BM == 3) ? (const void*)((const float*)Bg + zi * sB)
                                         : (const void*)((const __bf16*)Bg + zi * sB);
    const int kbeg = kPerZ ? (int)zi * kPerZ : 0;

    // Fragment row indices (swizzled for TN-staged tiles), k-independent.
    int rowA[4], rowB[4];
#pragma unroll
    for (int i = 0; i < 4; i++) {
        int ra = wm * 64 + i * 16 + t;
        int rb = wn * 64 + i * 16 + t;
        rowA[i] = (AM >= 2) ? (ra ^ ((ra >> 3) & 7)) : ra;
        rowB[i] = (BM >= 2) ? (rb ^ ((rb >> 3) & 7)) : rb;
    }

    f32x4 acc[4][4];
#pragma unroll
    for (int i = 0; i < 4; i++)
#pragma unroll
        for (int j = 0; j < 4; j++) { f32x4 z = {0.f,0.f,0.f,0.f}; acc[i][j] = z; }

    for (int k0 = kbeg; k0 < kbeg + Klen; k0 += 64) {
        stage_op<AM>(A, lda, m0, k0, As, tid);
        stage_op<BM>(B, ldb, n0, k0, Bs, tid);
        __syncthreads();
#pragma unroll
        for (int kk = 0; kk < 2; kk++) {
            bf16x8 af[4], bfv[4];
#pragma unroll
            for (int i = 0; i < 4; i++)
                af[i] = *(const bf16x8*)(&As[rowA[i] * 72 + kk*32 + quad*8]);
#pragma unroll
            for (int j = 0; j < 4; j++)
                bfv[j] = *(const bf16x8*)(&Bs[rowB[j] * 72 + kk*32 + quad*8]);
#pragma unroll
            for (int i = 0; i < 4; i++)
#pragma unroll
                for (int j = 0; j < 4; j++)
                    acc[i][j] = __builtin_amdgcn_mfma_f32_16x16x32_bf16(af[i], bfv[j], acc[i][j], 0, 0, 0);
        }
        __syncthreads();
    }

#pragma unroll
    for (int i = 0; i < 4; i++) {
        const int rowb = m0 + wm*64 + i*16 + quad*4;
#pragma unroll
        for (int j = 0; j < 4; j++) {
            const int col = n0 + wn*64 + j*16 + t;
            const float bv = biasg ? biasg[col] : 0.f;
#pragma unroll
            for (int r = 0; r < 4; r++) {
                const float v = acc[i][j][r] * scale + bv;
                if constexpr (OUT == 0) {
                    __bf16* C = (__bf16*)Cg + zi * sC;
                    C[(size_t)(rowb + r) * ldc + col] = (__bf16)v;
                } else if constexpr (OUT == 1) {
                    float* C = (float*)Cg + zi * sC;
                    C[(size_t)(rowb + r) * ldc + col] = v;
                } else {
                    float* C = (float*)Cg + zi * sC;
                    atomicAdd(&C[(size_t)(rowb + r) * ldc + col], v);
                }
            }
        }
    }
}

// u[e] = sum_s x[s][e].  64 blocks x 64 rows; u pre-zeroed.
__global__ __launch_bounds__(256) void colsum_u(const float* __restrict__ x, float* __restrict__ u)
{
    const int c = threadIdx.x * 4;
    float4 a = {0.f,0.f,0.f,0.f};
    const int r0 = blockIdx.x * 64;
    for (int r = 0; r < 64; r++) {
        float4 v = *(const float4*)(x + (size_t)(r0 + r) * E_DIM + c);
        a.x += v.x; a.y += v.y; a.z += v.z; a.w += v.w;
    }
    atomicAdd(&u[c+0], a.x); atomicAdd(&u[c+1], a.y);
    atomicAdd(&u[c+2], a.z); atomicAdd(&u[c+3], a.w);
}

// kq[r] = Wk[r,:]·u ; qq[r] = Wq[r,:]·u  (r = h*E+j, 8192 rows each)
__global__ __launch_bounds__(256) void gemv_u(
    const float* __restrict__ Wk, const float* __restrict__ Wq,
    const float* __restrict__ u, float* __restrict__ kq, float* __restrict__ qq)
{
    const int gw = blockIdx.x * 4 + (threadIdx.x >> 6);
    const int lane = threadIdx.x & 63;
    const float* W = (gw < 8192) ? Wk + (size_t)gw * E_DIM
                                 : Wq + (size_t)(gw - 8192) * E_DIM;
    float s = 0.f;
#pragma unroll
    for (int i = 0; i < 4; i++) {
        float4 w = *(const float4*)(W + lane*16 + i*4);
        float4 z = *(const float4*)(u + lane*16 + i*4);
        s += w.x*z.x + w.y*z.y + w.z*z.z + w.w*z.w;
    }
#pragma unroll
    for (int o = 32; o > 0; o >>= 1) s += __shfl_down(s, o);
    if (lane == 0) { if (gw < 8192) kq[gw] = s; else qq[gw - 8192] = s; }
}

// zb[h*E+f] = sum_o bv[h][o] * A[h][o][f]; zb pre-zeroed. grid (4,8,4)
__global__ __launch_bounds__(256) void colsum_zb(
    const __bf16* __restrict__ Ab, const float* __restrict__ bv, float* __restrict__ zb)
{
    const int h = blockIdx.y;
    const int f = blockIdx.x * 256 + threadIdx.x;
    const int o0 = blockIdx.z * 256;
    const __bf16* A = Ab + (size_t)h * E_DIM * E_DIM + (size_t)o0 * E_DIM + f;
    const float* bvh = bv + h * E_DIM + o0;
    float s = 0.f;
    for (int o = 0; o < 256; o++) s += bvh[o] * (float)A[(size_t)o * E_DIM];
    atomicAdd(&zb[h * E_DIM + f], s);
}

// oc[g] = zb·Wz[g,:] + bz[g]   (K=8192, one wave per row)
__global__ __launch_bounds__(256) void gemv_oc(
    const float* __restrict__ Wz, const float* __restrict__ zb,
    const float* __restrict__ bz, float* __restrict__ oc)
{
    const int gw = blockIdx.x * 4 + (threadIdx.x >> 6);
    const int lane = threadIdx.x & 63;
    const float* W = Wz + (size_t)gw * (H_DIM * E_DIM);
    float s = 0.f;
#pragma unroll
    for (int i = 0; i < 32; i++) {
        float4 w = *(const float4*)(W + i*256 + lane*4);
        float4 z = *(const float4*)(zb + i*256 + lane*4);
        s += w.x*z.x + w.y*z.y + w.z*z.z + w.w*z.w;
    }
#pragma unroll
    for (int o = 32; o > 0; o >>= 1) s += __shfl_down(s, o);
    if (lane == 0) oc[gw] = s + bz[gw];
}

// softmax over f with fused rank-1 bias terms and 1/sqrt(E) scale.
// row = h*E + j. val = (raw + kq_j*bq_f + bk_j*qq_f + S*bk_j*bq_f)/32
__global__ __launch_bounds__(256) void softmax_fused(
    const float* __restrict__ Sc, const float* __restrict__ kq,
    const float* __restrict__ qq, const float* __restrict__ bk,
    const float* __restrict__ bq, __bf16* __restrict__ Aout)
{
    __shared__ float red[4];
    const int row = blockIdx.x;
    const int h = row >> 10;
    const int tid = threadIdx.x, lane = tid & 63, wave = tid >> 6;
    const float kqj = kq[row], bkj = bk[row];
    const float cst = (float)S_DIM * bkj;

    float4 v = ((const float4*)(Sc + (size_t)row * E_DIM))[tid];
    const int c = tid * 4;
    float4 qv = *(const float4*)(qq + (h << 10) + c);
    float4 bv = *(const float4*)(bq + (h << 10) + c);
    v.x = (v.x + kqj*bv.x + bkj*qv.x + cst*bv.x) * 0.03125f;
    v.y = (v.y + kqj*bv.y + bkj*qv.y + cst*bv.y) * 0.03125f;
    v.z = (v.z + kqj*bv.z + bkj*qv.z + cst*bv.z) * 0.03125f;
    v.w = (v.w + kqj*bv.w + bkj*qv.w + cst*bv.w) * 0.03125f;

    float m = fmaxf(fmaxf(v.x, v.y), fmaxf(v.z, v.w));
#pragma unroll
    for (int o = 32; o > 0; o >>= 1) m = fmaxf(m, __shfl_down(m, o));
    if (lane == 0) red[wave] = m;
    __syncthreads();
    m = fmaxf(fmaxf(red[0], red[1]), fmaxf(red[2], red[3]));
    __syncthreads();

    const float e0 = __expf(v.x - m), e1 = __expf(v.y - m);
    const float e2 = __expf(v.z - m), e3 = __expf(v.w - m);
    float s = e0 + e1 + e2 + e3;
#pragma unroll
    for (int o = 32; o > 0; o >>= 1) s += __shfl_down(s, o);
    if (lane == 0) red[wave] = s;
    __syncthreads();
    s = red[0] + red[1] + red[2] + red[3];
    const float inv = 1.f / s;

    __bf16* out = Aout + (size_t)row * E_DIM + c;
    out[0] = (__bf16)(e0*inv); out[1] = (__bf16)(e1*inv);
    out[2] = (__bf16)(e2*inv); out[3] = (__bf16)(e3*inv);
}

// LN + residual (fp32 in/out, optional bf16 copy)
template <bool WRITE_BF16>
__global__ __launch_bounds__(256) void ln_residual(
    const float* __restrict__ X, const float* __restrict__ resid,
    const float* __restrict__ g, const float* __restrict__ b,
    __bf16* __restrict__ outB, float* __restrict__ outF)
{
    __shared__ float redS[4], redQ[4];
    const int row = blockIdx.x;
    const int tid = threadIdx.x, lane = tid & 63, wave = tid >> 6;

    float4 v = ((const float4*)(X + (size_t)row * E_DIM))[tid];
    float s = v.x + v.y + v.z + v.w;
    float q = v.x*v.x + v.y*v.y + v.z*v.z + v.w*v.w;
#pragma unroll
    for (int o = 32; o > 0; o >>= 1) { s += __shfl_down(s, o); q += __shfl_down(q, o); }
    if (lane == 0) { redS[wave] = s; redQ[wave] = q; }
    __syncthreads();
    s = redS[0]+redS[1]+redS[2]+redS[3];
    q = redQ[0]+redQ[1]+redQ[2]+redQ[3];

    const float mean = s * (1.f / E_DIM);
    const float var  = q * (1.f / E_DIM) - mean * mean;
    const float rstd = rsqrtf(var + 1e-5f);

    const int c0 = tid * 4;
    float4 rv = ((const float4*)(resid + (size_t)row * E_DIM))[tid];
    const float res[4] = {rv.x, rv.y, rv.z, rv.w};
    const float* vp = &v.x;
#pragma unroll
    for (int i = 0; i < 4; i++) {
        const float o = (vp[i] - mean) * rstd * g[c0+i] + b[c0+i] + res[i];
        outF[(size_t)row * E_DIM + c0 + i] = o;
        if constexpr (WRITE_BF16) outB[(size_t)row * E_DIM + c0 + i] = (__bf16)o;
    }
}

// ---------------------------------------------------------------------------
extern "C" void kernel_launch(void* const* d_in, const int* in_sizes, int n_in,
                              void* d_out, int out_size, void* d_ws, size_t ws_size,
                              hipStream_t stream)
{
    const float* x   = (const float*)d_in[0];
    const float* Wq  = (const float*)d_in[1];
    const float* bq  = (const float*)d_in[2];
    const float* Wk  = (const float*)d_in[3];
    const float* bk  = (const float*)d_in[4];
    const float* Wv  = (const float*)d_in[5];
    const float* bv  = (const float*)d_in[6];
    const float* Wz  = (const float*)d_in[7];
    const float* bz  = (const float*)d_in[8];
    const float* g1  = (const float*)d_in[9];
    const float* b1  = (const float*)d_in[10];
    const float* Wf  = (const float*)d_in[11];
    const float* bfp = (const float*)d_in[12];
    const float* g2  = (const float*)d_in[13];
    const float* b2  = (const float*)d_in[14];

    char* ws = (char*)d_ws;
    const long long EE = (long long)E_DIM * E_DIM;
    const size_t MB = 1024ull * 1024ull;

    float*  Gf   = (float*) (ws);                 //  4 MiB  x^T x
    float*  PTf  = (float*) (ws + 4*MB);          //  4 MiB  P^T[g][e]
    float*  u    = (float*) (ws + 8*MB);          //  4 KiB
    float*  kq   = (float*) (ws + 8*MB + 65536);  // 32 KiB
    float*  qq   = (float*) (ws + 8*MB + 131072); // 32 KiB
    float*  zb   = (float*) (ws + 8*MB + 196608); // 32 KiB
    float*  oc   = (float*) (ws + 8*MB + 262144); //  4 KiB
    __bf16* Tb   = (__bf16*)(ws + 16*MB);         // 16 MiB  Wk_h G
    float*  Sc   = (float*) (ws + 32*MB);         // 32 MiB  raw scores
    __bf16* Ab   = (__bf16*)(ws + 64*MB);         // 16 MiB  softmax
    __bf16* Mcat = (__bf16*)(ws + 80*MB);         // 16 MiB  [e][h*E+f]
    float*  Ob   = (float*) (ws + 96*MB);         // 16 MiB
    __bf16* LN1b = (__bf16*)(ws + 112*MB);        //  8 MiB
    float*  LN1f = (float*) (ws + 120*MB);        // 16 MiB
    float*  FNb  = (float*) (ws + 136*MB);        // 16 MiB  (end 152 MiB)

    dim3 blk(256);
    dim3 gEE(8, 8, 8);          // per-head / split-K EEE GEMMs
    dim3 gSE(8, 32, 1);         // [S,E] output GEMMs

    // zero split-K accumulators + vector accumulators (ws is 0xAA-poisoned)
    hipMemsetAsync(Gf,  0, 4*MB, stream);
    hipMemsetAsync(PTf, 0, 4*MB, stream);
    hipMemsetAsync(u,   0, E_DIM*4, stream);
    hipMemsetAsync(zb,  0, H_DIM*E_DIM*4, stream);

    // u = colsum(x)
    colsum_u<<<dim3(64), blk, 0, stream>>>(x, u);
    // G = x^T x  (TN both fp32, split-K 8x512, atomic f32)
    gemm128<3, 3, 2><<<gEE, blk, 0, stream>>>(
        x, x, (void*)Gf, nullptr, 512, 512, E_DIM, E_DIM, E_DIM, 0, 0, 0, 1.f);
    // kq = Wk u ; qq = Wq u
    gemv_u<<<dim3(4096), blk, 0, stream>>>(Wk, Wq, u, kq, qq);
    // T_h = Wk_h G  (B uses G symmetry: no transpose)
    gemm128<1, 1, 0><<<gEE, blk, 0, stream>>>(
        Wk, Gf, (void*)Tb, nullptr, E_DIM, 0, E_DIM, E_DIM, E_DIM, EE, 0, EE, 1.f);
    // scores_raw_h = T_h Wq_h^T
    gemm128<0, 1, 1><<<gEE, blk, 0, stream>>>(
        Tb, Wq, (void*)Sc, nullptr, E_DIM, 0, E_DIM, E_DIM, E_DIM, EE, EE, EE, 1.f);
    // A_h = softmax((scores_raw + rank1)/32)
    softmax_fused<<<dim3(H_DIM * E_DIM), blk, 0, stream>>>(Sc, kq, qq, bk, bq, Ab);
    // Mcat[e][h*E+f] = (Wv_h^T A_h)[e][f]  (TN both)
    gemm128<3, 2, 0><<<gEE, blk, 0, stream>>>(
        Wv, Ab, (void*)Mcat, nullptr, E_DIM, 0, E_DIM, E_DIM, H_DIM * E_DIM,
        EE, EE, E_DIM, 1.f);
    // zb = bv^T A  ;  oc = Wz zb + bz
    colsum_zb<<<dim3(4, 8, 4), blk, 0, stream>>>(Ab, bv, zb);
    gemv_oc<<<dim3(256), blk, 0, stream>>>(Wz, zb, bz, oc);
    // PT[g][e] = sum_F Wz[g][F] Mcat[e][F]  (split-K 8x1024, atomic f32)
    gemm128<1, 0, 2><<<gEE, blk, 0, stream>>>(
        Wz, Mcat, (void*)PTf, nullptr, 1024, 1024, H_DIM * E_DIM, H_DIM * E_DIM,
        E_DIM, 0, 0, 0, 1.f);
    // O = x PT^T + oc
    gemm128<1, 1, 1><<<gSE, blk, 0, stream>>>(
        x, PTf, (void*)Ob, oc, E_DIM, 0, E_DIM, E_DIM, E_DIM, 0, 0, 0, 1.f);
    // LN1 = LN(O) + x
    ln_residual<true><<<dim3(S_DIM), blk, 0, stream>>>(Ob, x, g1, b1, LN1b, LN1f);
    // FN = LN1 Wf^T + bf
    gemm128<0, 1, 1><<<gSE, blk, 0, stream>>>(
        LN1b, Wf, (void*)FNb, bfp, E_DIM, 0, E_DIM, E_DIM, E_DIM, 0, 0, 0, 1.f);
    // out = LN(FN) + LN1
    ln_residual<false><<<dim3(S_DIM), blk, 0, stream>>>(
        FNb, LN1f, g2, b2, nullptr, (float*)d_out);
}

// Round 5
// 523.494 us; speedup vs baseline: 2.7661x; 1.0599x over previous
//
#include <hip/hip_runtime.h>

#define S_DIM 4096
#define E_DIM 1024
#define H_DIM 8

typedef __bf16 bf16x8 __attribute__((ext_vector_type(8)));
typedef float  f32x4  __attribute__((ext_vector_type(4)));

// Async global->LDS, 16B per lane. LDS dest is wave-uniform base + lane*16.
__device__ __forceinline__ void async16(const __bf16* gsrc, __bf16* lbase, int lane)
{
#if __has_builtin(__builtin_amdgcn_global_load_lds)
    __builtin_amdgcn_global_load_lds(
        (const __attribute__((address_space(1))) unsigned int*)gsrc,
        (__attribute__((address_space(3))) unsigned int*)lbase, 16, 0, 0);
#else
    ((int4*)lbase)[lane] = *(const int4*)gsrc;
#endif
}

// ---------------------------------------------------------------------------
// Operand staging into LDS (bf16 sources only).
// MODE 0: NT [mn,k] k-contig -> async global_load_lds, tile stride 64 (no pad)
// MODE 2: TN [k,mn] k-major  -> transpose via packed b64, static XOR swizzle,
//         tile stride 72. True col c lives at LDS row (c&~7)|((c&7)^((c>>3)&7)).
// ---------------------------------------------------------------------------
template <int MODE>
__device__ __forceinline__ void stage_op(const __bf16* __restrict__ src, int ld,
                                         int mn0, int k0, __bf16* lds, int tid)
{
    if constexpr (MODE == 0) {
        const int w = tid >> 6, l = tid & 63;
        const int r8 = l >> 3, c8 = (l & 7) << 3;
#pragma unroll
        for (int i = 0; i < 4; i++) {
            const int rbase = w * 32 + i * 8;
            const __bf16* g = src + (size_t)(mn0 + rbase + r8) * ld + k0 + c8;
            async16(g, &lds[rbase * 64], l);
        }
    } else {
        // cols mn0 + (tid&15)*8 .. +8 ; krows k0 + (tid>>4)*4 .. +4
        const int cg = tid & 15, kg = tid >> 4;
        __bf16 h[4][8];
#pragma unroll
        for (int r = 0; r < 4; r++) {
            const __bf16* s = src + (size_t)(k0 + kg * 4 + r) * ld + mn0 + cg * 8;
            *(int4*)&h[r][0] = *(const int4*)s;
        }
        const int xr = cg & 7;
#pragma unroll
        for (int j = 0; j < 8; j++) {            // j static -> h[][] in VGPRs
            union { __bf16 q[4]; unsigned long long v; } u;
            u.q[0]=h[0][j]; u.q[1]=h[1][j]; u.q[2]=h[2][j]; u.q[3]=h[3][j];
            const int scol = cg * 8 + (j ^ xr);  // swizzle in address only
            *(unsigned long long*)&lds[scol * 72 + kg * 4] = u.v;
        }
    }
}

// ---------------------------------------------------------------------------
// 128x128-tile bf16 MFMA GEMM: C[m,n] = scale*sum_k A[m,k]B[n,k] (+bias[n]).
// OUT: 0=bf16 store, 1=fp32 store, 2=fp32 atomicAdd (split-K; bias ignored).
// kPerZ>0: blockIdx.z selects K-chunk; sC then offsets per-chunk partials.
// Otherwise z indexes batch via element strides sA/sB/sC.
// ---------------------------------------------------------------------------
template <int AM, int BM, int OUT>
__global__ __launch_bounds__(256) void gemm128(
    const __bf16* __restrict__ Ag, const __bf16* __restrict__ Bg,
    void* __restrict__ Cg, const float* __restrict__ biasg,
    int Klen, int kPerZ, int lda, int ldb, int ldc,
    long long sA, long long sB, long long sC, float scale)
{
    __shared__ __bf16 As[128 * 72];
    __shared__ __bf16 Bs[128 * 72];
    constexpr int SA = (AM == 2) ? 72 : 64;
    constexpr int SB = (BM == 2) ? 72 : 64;

    const int tid  = threadIdx.x;
    const int lane = tid & 63;
    const int wave = tid >> 6;
    const int t    = lane & 15;
    const int quad = lane >> 4;
    const int wm   = wave >> 1;
    const int wn   = wave & 1;
    const int m0   = blockIdx.y * 128;
    const int n0   = blockIdx.x * 128;
    const size_t zi = blockIdx.z;

    const __bf16* A = (kPerZ == 0) ? Ag + zi * sA : Ag;
    const __bf16* B = (kPerZ == 0) ? Bg + zi * sB : Bg;
    const int kbeg = kPerZ ? (int)zi * kPerZ : 0;

    // Fragment row indices (swizzled for TN-staged tiles), k-independent.
    int rowA[4], rowB[4];
#pragma unroll
    for (int i = 0; i < 4; i++) {
        int ra = wm * 64 + i * 16 + t;
        int rb = wn * 64 + i * 16 + t;
        rowA[i] = (AM == 2) ? (ra ^ ((ra >> 3) & 7)) : ra;
        rowB[i] = (BM == 2) ? (rb ^ ((rb >> 3) & 7)) : rb;
    }

    f32x4 acc[4][4];
#pragma unroll
    for (int i = 0; i < 4; i++)
#pragma unroll
        for (int j = 0; j < 4; j++) { f32x4 z = {0.f,0.f,0.f,0.f}; acc[i][j] = z; }

    for (int k0 = kbeg; k0 < kbeg + Klen; k0 += 64) {
        stage_op<AM>(A, lda, m0, k0, As, tid);
        stage_op<BM>(B, ldb, n0, k0, Bs, tid);
        __syncthreads();
#pragma unroll
        for (int kk = 0; kk < 2; kk++) {
            bf16x8 af[4], bfv[4];
#pragma unroll
            for (int i = 0; i < 4; i++)
                af[i] = *(const bf16x8*)(&As[rowA[i] * SA + kk*32 + quad*8]);
#pragma unroll
            for (int j = 0; j < 4; j++)
                bfv[j] = *(const bf16x8*)(&Bs[rowB[j] * SB + kk*32 + quad*8]);
#pragma unroll
            for (int i = 0; i < 4; i++)
#pragma unroll
                for (int j = 0; j < 4; j++)
                    acc[i][j] = __builtin_amdgcn_mfma_f32_16x16x32_bf16(af[i], bfv[j], acc[i][j], 0, 0, 0);
        }
        __syncthreads();
    }

#pragma unroll
    for (int i = 0; i < 4; i++) {
        const int rowb = m0 + wm*64 + i*16 + quad*4;
#pragma unroll
        for (int j = 0; j < 4; j++) {
            const int col = n0 + wn*64 + j*16 + t;
            const float bv = biasg ? biasg[col] : 0.f;
#pragma unroll
            for (int r = 0; r < 4; r++) {
                const float v = acc[i][j][r] * scale + bv;
                if constexpr (OUT == 0) {
                    __bf16* C = (__bf16*)Cg + zi * sC;
                    C[(size_t)(rowb + r) * ldc + col] = (__bf16)v;
                } else if constexpr (OUT == 1) {
                    float* C = (float*)Cg + zi * sC;
                    C[(size_t)(rowb + r) * ldc + col] = v;
                } else {
                    float* C = (float*)Cg;
                    atomicAdd(&C[(size_t)(rowb + r) * ldc + col], v);
                }
            }
        }
    }
}

// fp32 -> bf16, 8 elems/thread, exact-size grid (n multiple of 2048).
__global__ __launch_bounds__(256) void cvt_bf16(
    const float* __restrict__ in, __bf16* __restrict__ out)
{
    const size_t i = ((size_t)blockIdx.x * 256 + threadIdx.x) * 8;
    float4 a = *(const float4*)(in + i);
    float4 b = *(const float4*)(in + i + 4);
    union { __bf16 h[8]; int4 v; } u;
    u.h[0]=(__bf16)a.x; u.h[1]=(__bf16)a.y; u.h[2]=(__bf16)a.z; u.h[3]=(__bf16)a.w;
    u.h[4]=(__bf16)b.x; u.h[5]=(__bf16)b.y; u.h[6]=(__bf16)b.z; u.h[7]=(__bf16)b.w;
    *(int4*)(out + i) = u.v;
}

// u[e] = sum_s x[s][e].  64 blocks x 64 rows; u pre-zeroed.
__global__ __launch_bounds__(256) void colsum_u(const float* __restrict__ x, float* __restrict__ u)
{
    const int c = threadIdx.x * 4;
    float4 a = {0.f,0.f,0.f,0.f};
    const int r0 = blockIdx.x * 64;
    for (int r = 0; r < 64; r++) {
        float4 v = *(const float4*)(x + (size_t)(r0 + r) * E_DIM + c);
        a.x += v.x; a.y += v.y; a.z += v.z; a.w += v.w;
    }
    atomicAdd(&u[c+0], a.x); atomicAdd(&u[c+1], a.y);
    atomicAdd(&u[c+2], a.z); atomicAdd(&u[c+3], a.w);
}

// kq[r] = Wk[r,:]·u ; qq[r] = Wq[r,:]·u  (r = h*E+j, 8192 rows each)
__global__ __launch_bounds__(256) void gemv_u(
    const float* __restrict__ Wk, const float* __restrict__ Wq,
    const float* __restrict__ u, float* __restrict__ kq, float* __restrict__ qq)
{
    const int gw = blockIdx.x * 4 + (threadIdx.x >> 6);
    const int lane = threadIdx.x & 63;
    const float* W = (gw < 8192) ? Wk + (size_t)gw * E_DIM
                                 : Wq + (size_t)(gw - 8192) * E_DIM;
    float s = 0.f;
#pragma unroll
    for (int i = 0; i < 4; i++) {
        float4 w = *(const float4*)(W + lane*16 + i*4);
        float4 z = *(const float4*)(u + lane*16 + i*4);
        s += w.x*z.x + w.y*z.y + w.z*z.z + w.w*z.w;
    }
#pragma unroll
    for (int o = 32; o > 0; o >>= 1) s += __shfl_down(s, o);
    if (lane == 0) { if (gw < 8192) kq[gw] = s; else qq[gw - 8192] = s; }
}

// zb[h*E+f] = sum_o bv[h][o] * A[h][o][f]; zb pre-zeroed. grid (4,8,4)
__global__ __launch_bounds__(256) void colsum_zb(
    const __bf16* __restrict__ Ab, const float* __restrict__ bv, float* __restrict__ zb)
{
    const int h = blockIdx.y;
    const int f = blockIdx.x * 256 + threadIdx.x;
    const int o0 = blockIdx.z * 256;
    const __bf16* A = Ab + (size_t)h * E_DIM * E_DIM + (size_t)o0 * E_DIM + f;
    const float* bvh = bv + h * E_DIM + o0;
    float s = 0.f;
    for (int o = 0; o < 256; o++) s += bvh[o] * (float)A[(size_t)o * E_DIM];
    atomicAdd(&zb[h * E_DIM + f], s);
}

// oc[g] = zb·Wz[g,:] + bz[g]   (K=8192, one wave per row)
__global__ __launch_bounds__(256) void gemv_oc(
    const float* __restrict__ Wz, const float* __restrict__ zb,
    const float* __restrict__ bz, float* __restrict__ oc)
{
    const int gw = blockIdx.x * 4 + (threadIdx.x >> 6);
    const int lane = threadIdx.x & 63;
    const float* W = Wz + (size_t)gw * (H_DIM * E_DIM);
    float s = 0.f;
#pragma unroll
    for (int i = 0; i < 32; i++) {
        float4 w = *(const float4*)(W + i*256 + lane*4);
        float4 z = *(const float4*)(zb + i*256 + lane*4);
        s += w.x*z.x + w.y*z.y + w.z*z.z + w.w*z.w;
    }
#pragma unroll
    for (int o = 32; o > 0; o >>= 1) s += __shfl_down(s, o);
    if (lane == 0) oc[gw] = s + bz[gw];
}

// softmax over f with fused rank-1 bias terms and 1/sqrt(E) scale.
// row = h*E + j. val = (raw + kq_j*bq_f + bk_j*qq_f + S*bk_j*bq_f)/32
__global__ __launch_bounds__(256) void softmax_fused(
    const float* __restrict__ Sc, const float* __restrict__ kq,
    const float* __restrict__ qq, const float* __restrict__ bk,
    const float* __restrict__ bq, __bf16* __restrict__ Aout)
{
    __shared__ float red[4];
    const int row = blockIdx.x;
    const int h = row >> 10;
    const int tid = threadIdx.x, lane = tid & 63, wave = tid >> 6;
    const float kqj = kq[row], bkj = bk[row];
    const float cst = (float)S_DIM * bkj;

    float4 v = ((const float4*)(Sc + (size_t)row * E_DIM))[tid];
    const int c = tid * 4;
    float4 qv = *(const float4*)(qq + (h << 10) + c);
    float4 bv = *(const float4*)(bq + (h << 10) + c);
    v.x = (v.x + kqj*bv.x + bkj*qv.x + cst*bv.x) * 0.03125f;
    v.y = (v.y + kqj*bv.y + bkj*qv.y + cst*bv.y) * 0.03125f;
    v.z = (v.z + kqj*bv.z + bkj*qv.z + cst*bv.z) * 0.03125f;
    v.w = (v.w + kqj*bv.w + bkj*qv.w + cst*bv.w) * 0.03125f;

    float m = fmaxf(fmaxf(v.x, v.y), fmaxf(v.z, v.w));
#pragma unroll
    for (int o = 32; o > 0; o >>= 1) m = fmaxf(m, __shfl_down(m, o));
    if (lane == 0) red[wave] = m;
    __syncthreads();
    m = fmaxf(fmaxf(red[0], red[1]), fmaxf(red[2], red[3]));
    __syncthreads();

    const float e0 = __expf(v.x - m), e1 = __expf(v.y - m);
    const float e2 = __expf(v.z - m), e3 = __expf(v.w - m);
    float s = e0 + e1 + e2 + e3;
#pragma unroll
    for (int o = 32; o > 0; o >>= 1) s += __shfl_down(s, o);
    if (lane == 0) red[wave] = s;
    __syncthreads();
    s = red[0] + red[1] + red[2] + red[3];
    const float inv = 1.f / s;

    __bf16* out = Aout + (size_t)row * E_DIM + c;
    out[0] = (__bf16)(e0*inv); out[1] = (__bf16)(e1*inv);
    out[2] = (__bf16)(e2*inv); out[3] = (__bf16)(e3*inv);
}

// LN + residual. X = sum of NPART fp32 partials (stride S*E) + optional
// per-column bias cb. out = LN(X)*g + b + resid.
template <int NPART, bool CB, bool WRITE_BF16>
__global__ __launch_bounds__(256) void ln_residual(
    const float* __restrict__ X, const float* __restrict__ cb,
    const float* __restrict__ resid,
    const float* __restrict__ g, const float* __restrict__ b,
    __bf16* __restrict__ outB, float* __restrict__ outF)
{
    __shared__ float redS[4], redQ[4];
    const int row = blockIdx.x;
    const int tid = threadIdx.x, lane = tid & 63, wave = tid >> 6;
    const size_t SE = (size_t)S_DIM * E_DIM;

    float4 v = ((const float4*)(X + (size_t)row * E_DIM))[tid];
    if constexpr (NPART == 2) {
        float4 v1 = ((const float4*)(X + SE + (size_t)row * E_DIM))[tid];
        v.x += v1.x; v.y += v1.y; v.z += v1.z; v.w += v1.w;
    }
    if constexpr (CB) {
        float4 cv = ((const float4*)cb)[tid];
        v.x += cv.x; v.y += cv.y; v.z += cv.z; v.w += cv.w;
    }
    float s = v.x + v.y + v.z + v.w;
    float q = v.x*v.x + v.y*v.y + v.z*v.z + v.w*v.w;
#pragma unroll
    for (int o = 32; o > 0; o >>= 1) { s += __shfl_down(s, o); q += __shfl_down(q, o); }
    if (lane == 0) { redS[wave] = s; redQ[wave] = q; }
    __syncthreads();
    s = redS[0]+redS[1]+redS[2]+redS[3];
    q = redQ[0]+redQ[1]+redQ[2]+redQ[3];

    const float mean = s * (1.f / E_DIM);
    const float var  = q * (1.f / E_DIM) - mean * mean;
    const float rstd = rsqrtf(var + 1e-5f);

    const int c0 = tid * 4;
    float4 rv = ((const float4*)(resid + (size_t)row * E_DIM))[tid];
    const float res[4] = {rv.x, rv.y, rv.z, rv.w};
    const float* vp = &v.x;
#pragma unroll
    for (int i = 0; i < 4; i++) {
        const float o = (vp[i] - mean) * rstd * g[c0+i] + b[c0+i] + res[i];
        outF[(size_t)row * E_DIM + c0 + i] = o;
        if constexpr (WRITE_BF16) outB[(size_t)row * E_DIM + c0 + i] = (__bf16)o;
    }
}

// ---------------------------------------------------------------------------
extern "C" void kernel_launch(void* const* d_in, const int* in_sizes, int n_in,
                              void* d_out, int out_size, void* d_ws, size_t ws_size,
                              hipStream_t stream)
{
    const float* x   = (const float*)d_in[0];
    const float* Wq  = (const float*)d_in[1];
    const float* bq  = (const float*)d_in[2];
    const float* Wk  = (const float*)d_in[3];
    const float* bk  = (const float*)d_in[4];
    const float* Wv  = (const float*)d_in[5];
    const float* bv  = (const float*)d_in[6];
    const float* Wz  = (const float*)d_in[7];
    const float* bz  = (const float*)d_in[8];
    const float* g1  = (const float*)d_in[9];
    const float* b1  = (const float*)d_in[10];
    const float* Wf  = (const float*)d_in[11];
    const float* bfp = (const float*)d_in[12];
    const float* g2  = (const float*)d_in[13];
    const float* b2  = (const float*)d_in[14];

    char* ws = (char*)d_ws;
    const long long EE = (long long)E_DIM * E_DIM;
    const long long SE = (long long)S_DIM * E_DIM;
    const size_t MB = 1024ull * 1024ull;

    // bf16 operand copies
    __bf16* xb   = (__bf16*)(ws);             //  8 MiB
    __bf16* Wqb  = (__bf16*)(ws +   8*MB);    // 16 MiB
    __bf16* Wkb  = (__bf16*)(ws +  24*MB);    // 16 MiB
    __bf16* Wvb  = (__bf16*)(ws +  40*MB);    // 16 MiB
    __bf16* Wzb  = (__bf16*)(ws +  56*MB);    // 16 MiB
    __bf16* Wfb  = (__bf16*)(ws +  72*MB);    //  2 MiB
    float*  Gf   = (float*) (ws +  74*MB);    //  4 MiB
    __bf16* Gb   = (__bf16*)(ws +  78*MB);    //  2 MiB
    float*  PTf  = (float*) (ws +  80*MB);    //  4 MiB
    __bf16* PTb  = (__bf16*)(ws +  84*MB);    //  2 MiB
    float*  u    = (float*) (ws +  86*MB);
    float*  kq   = (float*) (ws +  86*MB +  65536);
    float*  qq   = (float*) (ws +  86*MB + 131072);
    float*  zb   = (float*) (ws +  86*MB + 196608);
    float*  oc   = (float*) (ws +  86*MB + 262144);
    __bf16* LN1b = (__bf16*)(ws +  87*MB);    //  8 MiB
    float*  LN1f = (float*) (ws +  95*MB);    // 16 MiB
    __bf16* Tb   = (__bf16*)(ws + 111*MB);    // 16 MiB  (dead after scores)
    float*  Sc   = (float*) (ws + 127*MB);    // 32 MiB  (dead after softmax)
    __bf16* Ab   = (__bf16*)(ws + 159*MB);    // 16 MiB  (dead after Mcat/zb)
    __bf16* Mcat = (__bf16*)(ws + 175*MB);    // 16 MiB  (dead after PT; end 191)
    float*  Ob   = (float*) (ws + 111*MB);    // 32 MiB  2 partials (over Tb+Sc lo)
    float*  FNb  = (float*) (ws + 143*MB);    // 32 MiB  2 partials (over Sc hi+Ab)

    dim3 blk(256);

    // zero accumulators (ws is 0xAA-poisoned)
    hipMemsetAsync(Gf,  0, 4*MB, stream);
    hipMemsetAsync(PTf, 0, 4*MB, stream);
    hipMemsetAsync(u,   0, E_DIM*4, stream);
    hipMemsetAsync(zb,  0, H_DIM*E_DIM*4, stream);

    // fp32 -> bf16 operand conversions
    cvt_bf16<<<dim3(2048), blk, 0, stream>>>(x,  xb);
    cvt_bf16<<<dim3(4096), blk, 0, stream>>>(Wq, Wqb);
    cvt_bf16<<<dim3(4096), blk, 0, stream>>>(Wk, Wkb);
    cvt_bf16<<<dim3(4096), blk, 0, stream>>>(Wv, Wvb);
    cvt_bf16<<<dim3(4096), blk, 0, stream>>>(Wz, Wzb);
    cvt_bf16<<<dim3(512),  blk, 0, stream>>>(Wf, Wfb);

    // u = colsum(x); kq = Wk u; qq = Wq u  (fp32 exact)
    colsum_u<<<dim3(64), blk, 0, stream>>>(x, u);
    gemv_u<<<dim3(4096), blk, 0, stream>>>(Wk, Wq, u, kq, qq);

    // G = x^T x  (TN both, split-K 8x512, atomic fp32) ; then bf16 copy
    gemm128<2, 2, 2><<<dim3(8, 8, 8), blk, 0, stream>>>(
        xb, xb, (void*)Gf, nullptr, 512, 512, E_DIM, E_DIM, E_DIM, 0, 0, 0, 1.f);
    cvt_bf16<<<dim3(512), blk, 0, stream>>>(Gf, Gb);

    // T_h = Wk_h G  (both NT async; G symmetric)
    gemm128<0, 0, 0><<<dim3(8, 8, 8), blk, 0, stream>>>(
        Wkb, Gb, (void*)Tb, nullptr, E_DIM, 0, E_DIM, E_DIM, E_DIM, EE, 0, EE, 1.f);
    // scores_raw_h = T_h Wq_h^T  (both NT async)
    gemm128<0, 0, 1><<<dim3(8, 8, 8), blk, 0, stream>>>(
        Tb, Wqb, (void*)Sc, nullptr, E_DIM, 0, E_DIM, E_DIM, E_DIM, EE, EE, EE, 1.f);
    // A_h = softmax((raw + rank1)/32)
    softmax_fused<<<dim3(H_DIM * E_DIM), blk, 0, stream>>>(Sc, kq, qq, bk, bq, Ab);

    // Mcat[e][h*E+f] = (Wv_h^T A_h)[e][f]  (TN both)
    gemm128<2, 2, 0><<<dim3(8, 8, 8), blk, 0, stream>>>(
        Wvb, Ab, (void*)Mcat, nullptr, E_DIM, 0, E_DIM, E_DIM, H_DIM * E_DIM,
        EE, EE, E_DIM, 1.f);
    // zb = bv^T A ; oc = Wz zb + bz
    colsum_zb<<<dim3(4, 8, 4), blk, 0, stream>>>(Ab, bv, zb);
    gemv_oc<<<dim3(256), blk, 0, stream>>>(Wz, zb, bz, oc);

    // PT[g][e] = sum_F Wz[g][F] Mcat[e][F]  (NT async, split-K 8x1024, atomic)
    gemm128<0, 0, 2><<<dim3(8, 8, 8), blk, 0, stream>>>(
        Wzb, Mcat, (void*)PTf, nullptr, 1024, 1024, H_DIM * E_DIM, H_DIM * E_DIM,
        E_DIM, 0, 0, 0, 1.f);
    cvt_bf16<<<dim3(512), blk, 0, stream>>>(PTf, PTb);

    // O partials = x PT^T  (split-K 2x512 -> 2 fp32 partials; bias oc in LN)
    gemm128<0, 0, 1><<<dim3(8, 32, 2), blk, 0, stream>>>(
        xb, PTb, (void*)Ob, nullptr, 512, 512, E_DIM, E_DIM, E_DIM, 0, 0, SE, 1.f);
    // LN1 = LN(O0+O1+oc)*g1+b1 + x
    ln_residual<2, true, true><<<dim3(S_DIM), blk, 0, stream>>>(
        Ob, oc, x, g1, b1, LN1b, LN1f);

    // FN partials = LN1 Wf^T  (split-K 2x512; bias bf in LN)
    gemm128<0, 0, 1><<<dim3(8, 32, 2), blk, 0, stream>>>(
        LN1b, Wfb, (void*)FNb, nullptr, 512, 512, E_DIM, E_DIM, E_DIM, 0, 0, SE, 1.f);
    // out = LN(FN0+FN1+bf)*g2+b2 + LN1
    ln_residual<2, true, false><<<dim3(S_DIM), blk, 0, stream>>>(
        FNb, bfp, LN1f, g2, b2, nullptr, (float*)d_out);
}